// Round 1
// baseline (1371.123 us; speedup 1.0000x reference)
//
#include <hip/hip_runtime.h>
#include <hip/hip_bf16.h>
#include <math.h>

// Problem constants
#define NB    4
#define LQ    512
#define LKV   8192
#define QDIM  1024
#define KVDIM 512
#define QKCH  256
#define VCH   256
#define NH    8
#define DHD   32          // per-head dim for q,k,v
#define EPS_LN 1e-5f

// ---------------------------------------------------------------------------
// LayerNorm statistics: one block per row, writes mean and rstd only.
// LN itself is applied on-the-fly while staging X tiles in the GEMM.
// ---------------------------------------------------------------------------
template<int K>
__global__ __launch_bounds__(256) void ln_stats_kernel(
    const float* __restrict__ x, float* __restrict__ mean, float* __restrict__ rstd)
{
    __shared__ float sm[4];
    constexpr int PT = K / 256;
    const size_t base = (size_t)blockIdx.x * K;
    float loc[PT];
    float s = 0.f;
#pragma unroll
    for (int i = 0; i < PT; ++i) {
        loc[i] = x[base + threadIdx.x + i * 256];
        s += loc[i];
    }
#pragma unroll
    for (int o = 32; o; o >>= 1) s += __shfl_down(s, o, 64);
    if ((threadIdx.x & 63) == 0) sm[threadIdx.x >> 6] = s;
    __syncthreads();
    const float mu = (sm[0] + sm[1] + sm[2] + sm[3]) * (1.0f / K);
    __syncthreads();
    float vs = 0.f;
#pragma unroll
    for (int i = 0; i < PT; ++i) { float d = loc[i] - mu; vs += d * d; }
#pragma unroll
    for (int o = 32; o; o >>= 1) vs += __shfl_down(vs, o, 64);
    if ((threadIdx.x & 63) == 0) sm[threadIdx.x >> 6] = vs;
    __syncthreads();
    if (threadIdx.x == 0) {
        mean[blockIdx.x] = mu;
        rstd[blockIdx.x] = rsqrtf((sm[0] + sm[1] + sm[2] + sm[3]) * (1.0f / K) + EPS_LN);
    }
}

// ---------------------------------------------------------------------------
// Y[M,N] = LayerNorm(X[M,K]) @ W[K,N] + bias
// 64x64 tile, BK=16, 256 threads, 4x4 micro-tile per thread.
// LN (mean/rstd/gamma/beta) applied while staging X into LDS.
// ---------------------------------------------------------------------------
__global__ __launch_bounds__(256) void gemm_ln_bias_kernel(
    const float* __restrict__ X,
    const float* __restrict__ mean, const float* __restrict__ rstd,
    const float* __restrict__ lng,  const float* __restrict__ lnb,
    const float* __restrict__ W,    const float* __restrict__ bias,
    float* __restrict__ Y, int M, int N, int K)
{
    // Xs stored transposed [k][m]; pad 68 keeps rows 16B-aligned (68*4=272),
    // store conflicts are 2-way (free), compute reads broadcast.
    __shared__ float Xs[16][68];
    __shared__ float Ws[16][64];

    const int bm = blockIdx.x * 64;
    const int bn = blockIdx.y * 64;
    const int t  = threadIdx.x;
    const int tm = (t >> 4) << 2;      // 0..60 step 4
    const int tn = (t & 15) << 2;      // 0..60 step 4
    // X loader: 1 float4 per thread, row lr, k-offset lk
    const int lr = t >> 2;             // 0..63
    const int lk = (t & 3) << 2;       // 0,4,8,12
    // W loader: 1 float4 per thread
    const int wk = t >> 4;             // 0..15
    const int wn = (t & 15) << 2;      // 0..60 step 4

    const int   xrow = bm + lr;
    const float mu   = mean[xrow];
    const float rs   = rstd[xrow];
    const float* xp  = X + (size_t)xrow * K;

    float acc[4][4] = {{0.f}};

    for (int k0 = 0; k0 < K; k0 += 16) {
        const float4 xv = *(const float4*)(xp + k0 + lk);
        const float4 gv = *(const float4*)(lng + k0 + lk);
        const float4 b2 = *(const float4*)(lnb + k0 + lk);
        Xs[lk + 0][lr] = (xv.x - mu) * rs * gv.x + b2.x;
        Xs[lk + 1][lr] = (xv.y - mu) * rs * gv.y + b2.y;
        Xs[lk + 2][lr] = (xv.z - mu) * rs * gv.z + b2.z;
        Xs[lk + 3][lr] = (xv.w - mu) * rs * gv.w + b2.w;
        *(float4*)&Ws[wk][wn] = *(const float4*)(W + (size_t)(k0 + wk) * N + bn + wn);
        __syncthreads();
#pragma unroll
        for (int kk = 0; kk < 16; ++kk) {
            const float4 a = *(const float4*)&Xs[kk][tm];
            const float4 b = *(const float4*)&Ws[kk][tn];
            acc[0][0] += a.x * b.x; acc[0][1] += a.x * b.y; acc[0][2] += a.x * b.z; acc[0][3] += a.x * b.w;
            acc[1][0] += a.y * b.x; acc[1][1] += a.y * b.y; acc[1][2] += a.y * b.z; acc[1][3] += a.y * b.w;
            acc[2][0] += a.z * b.x; acc[2][1] += a.z * b.y; acc[2][2] += a.z * b.z; acc[2][3] += a.z * b.w;
            acc[3][0] += a.w * b.x; acc[3][1] += a.w * b.y; acc[3][2] += a.w * b.z; acc[3][3] += a.w * b.w;
        }
        __syncthreads();
    }

    const float4 bb = *(const float4*)(bias + bn + tn);
#pragma unroll
    for (int i = 0; i < 4; ++i) {
        float4 o;
        o.x = acc[i][0] + bb.x;
        o.y = acc[i][1] + bb.y;
        o.z = acc[i][2] + bb.z;
        o.w = acc[i][3] + bb.w;
        *(float4*)(Y + (size_t)(bm + tm + i) * N + bn + tn) = o;
    }
}

// ---------------------------------------------------------------------------
// Flash attention, fp32. Grid: (LQ/32, B*H). Block: 256 threads.
// Thread (qi = t>>3, kg = t&7): owns q-row qi; computes 8 scores per K-tile;
// accumulates ctx for d = kg*4 .. kg*4+3. Online softmax per q-row.
// ---------------------------------------------------------------------------
__global__ __launch_bounds__(256) void attn_kernel(
    const float* __restrict__ Q,   // [B, LQ, H, 32]
    const float* __restrict__ K,   // [B, LKV, H, 32]
    const float* __restrict__ V,   // [B, LKV, H, 32]
    float* __restrict__ O)         // [B, LQ, H, 32]
{
    const int bh = blockIdx.y;             // b*8 + h
    const int b  = bh >> 3;
    const int h  = bh & 7;
    const int qt = blockIdx.x;             // q-tile (32 rows)
    const int t  = threadIdx.x;
    const int qi = t >> 3;                 // 0..31
    const int kg = t & 7;                  // 0..7

    __shared__ float Ks[64][33];           // stride 33: conflict-free scalar reads
    __shared__ float Vs[64][33];
    __shared__ float Ps[32][65];           // probs; stride 65 avoids 8-way on reads
    __shared__ float red[32][8];
    __shared__ float mrow[32], lrow[32], arow[32];

    const int qrow = qt * 32 + qi;
    const float* qp = Q + (((size_t)b * LQ + qrow) * NH + h) * DHD;
    const float scale = 0.1767766952966369f;  // 1/sqrt(32)
    float qreg[32];
#pragma unroll
    for (int d = 0; d < 32; ++d) qreg[d] = qp[d] * scale;

    float acc0 = 0.f, acc1 = 0.f, acc2 = 0.f, acc3 = 0.f;
    if (kg == 0) { mrow[qi] = -1e30f; lrow[qi] = 0.f; }

    const int lr = t >> 2;                 // K/V loader: row 0..63
    const int lc = (t & 3) * 8;            // col 0,8,16,24

    for (int kt = 0; kt < LKV; kt += 64) {
        // ---- stage K,V tile ----
        {
            const float* kp = K + (((size_t)b * LKV + kt + lr) * NH + h) * DHD + lc;
            const float* vp = V + (((size_t)b * LKV + kt + lr) * NH + h) * DHD + lc;
            const float4 k0 = *(const float4*)(kp);
            const float4 k1 = *(const float4*)(kp + 4);
            const float4 v0 = *(const float4*)(vp);
            const float4 v1 = *(const float4*)(vp + 4);
            Ks[lr][lc + 0] = k0.x; Ks[lr][lc + 1] = k0.y; Ks[lr][lc + 2] = k0.z; Ks[lr][lc + 3] = k0.w;
            Ks[lr][lc + 4] = k1.x; Ks[lr][lc + 5] = k1.y; Ks[lr][lc + 6] = k1.z; Ks[lr][lc + 7] = k1.w;
            Vs[lr][lc + 0] = v0.x; Vs[lr][lc + 1] = v0.y; Vs[lr][lc + 2] = v0.z; Vs[lr][lc + 3] = v0.w;
            Vs[lr][lc + 4] = v1.x; Vs[lr][lc + 5] = v1.y; Vs[lr][lc + 6] = v1.z; Vs[lr][lc + 7] = v1.w;
        }
        __syncthreads();   // (A) tiles visible

        // ---- scores: 8 per thread ----
        float s[8];
#pragma unroll
        for (int i = 0; i < 8; ++i) {
            const int kk = kg * 8 + i;
            float a = 0.f;
#pragma unroll
            for (int d = 0; d < 32; ++d) a += qreg[d] * Ks[kk][d];
            s[i] = a;
        }
        float lm = s[0];
#pragma unroll
        for (int i = 1; i < 8; ++i) lm = fmaxf(lm, s[i]);
        red[qi][kg] = lm;
        __syncthreads();   // (B) local maxima visible

        if (kg == 0) {
            float mo = mrow[qi];
            float mn = mo;
#pragma unroll
            for (int j = 0; j < 8; ++j) mn = fmaxf(mn, red[qi][j]);
            mrow[qi] = mn;
            const float al = __expf(mo - mn);
            arow[qi] = al;
            lrow[qi] *= al;
        }
        __syncthreads();   // (C) mnew/alpha visible

        const float mn = mrow[qi];
        const float al = arow[qi];
        float lsum = 0.f;
#pragma unroll
        for (int i = 0; i < 8; ++i) {
            const float p = __expf(s[i] - mn);
            Ps[qi][kg * 8 + i] = p;
            lsum += p;
        }
        red[qi][kg] = lsum;
        acc0 *= al; acc1 *= al; acc2 *= al; acc3 *= al;
        __syncthreads();   // (D) probs + partial sums visible

        if (kg == 0) {
            float ls = 0.f;
#pragma unroll
            for (int j = 0; j < 8; ++j) ls += red[qi][j];
            lrow[qi] += ls;
        }
        // ---- ctx accumulate: d = kg*4 .. +3 ----
        const int d0 = kg * 4;
#pragma unroll
        for (int kk = 0; kk < 64; ++kk) {
            const float p = Ps[qi][kk];
            acc0 += p * Vs[kk][d0 + 0];
            acc1 += p * Vs[kk][d0 + 1];
            acc2 += p * Vs[kk][d0 + 2];
            acc3 += p * Vs[kk][d0 + 3];
        }
        __syncthreads();   // (E) done with tiles/probs before overwrite
    }

    const float linv = 1.0f / lrow[qi];
    float4 o;
    o.x = acc0 * linv; o.y = acc1 * linv; o.z = acc2 * linv; o.w = acc3 * linv;
    *(float4*)(O + (((size_t)b * LQ + qrow) * NH + h) * DHD + kg * 4) = o;
}

// ---------------------------------------------------------------------------
extern "C" void kernel_launch(void* const* d_in, const int* in_sizes, int n_in,
                              void* d_out, int out_size, void* d_ws, size_t ws_size,
                              hipStream_t stream)
{
    const float* hidden = (const float*)d_in[0];   // [4,512,1024]
    const float* inputs = (const float*)d_in[1];   // [4,8192,512]
    const float* ln1g   = (const float*)d_in[2];
    const float* ln1b   = (const float*)d_in[3];
    const float* ln2g   = (const float*)d_in[4];
    const float* ln2b   = (const float*)d_in[5];
    const float* Wq     = (const float*)d_in[6];   // [1024,256]
    const float* bq     = (const float*)d_in[7];
    const float* Wk     = (const float*)d_in[8];   // [512,256]
    const float* bk     = (const float*)d_in[9];
    const float* Wv     = (const float*)d_in[10];  // [512,256]
    const float* bv     = (const float*)d_in[11];
    float* out = (float*)d_out;                    // [4,512,256]

    float* ws = (float*)d_ws;
    float* mean_h = ws;                                   // 2048
    float* rstd_h = mean_h + NB * LQ;                     // 2048
    float* mean_i = rstd_h + NB * LQ;                     // 32768
    float* rstd_i = mean_i + NB * LKV;                    // 32768
    float* qbuf   = rstd_i + NB * LKV;                    // 4*512*256
    float* kbuf   = qbuf + (size_t)NB * LQ * QKCH;        // 4*8192*256
    float* vbuf   = kbuf + (size_t)NB * LKV * QKCH;       // 4*8192*256

    ln_stats_kernel<QDIM><<<NB * LQ, 256, 0, stream>>>(hidden, mean_h, rstd_h);
    ln_stats_kernel<KVDIM><<<NB * LKV, 256, 0, stream>>>(inputs, mean_i, rstd_i);

    dim3 gq(NB * LQ / 64, QKCH / 64);
    gemm_ln_bias_kernel<<<gq, 256, 0, stream>>>(hidden, mean_h, rstd_h, ln1g, ln1b,
                                                Wq, bq, qbuf, NB * LQ, QKCH, QDIM);
    dim3 gk(NB * LKV / 64, QKCH / 64);
    gemm_ln_bias_kernel<<<gk, 256, 0, stream>>>(inputs, mean_i, rstd_i, ln2g, ln2b,
                                                Wk, bk, kbuf, NB * LKV, QKCH, KVDIM);
    gemm_ln_bias_kernel<<<gk, 256, 0, stream>>>(inputs, mean_i, rstd_i, ln2g, ln2b,
                                                Wv, bv, vbuf, NB * LKV, VCH, KVDIM);

    dim3 ga(LQ / 32, NB * NH);
    attn_kernel<<<ga, 256, 0, stream>>>(qbuf, kbuf, vbuf, out);
}

// Round 2
// 541.197 us; speedup vs baseline: 2.5335x; 2.5335x over previous
//
#include <hip/hip_runtime.h>
#include <hip/hip_bf16.h>
#include <math.h>

// Problem constants
#define NB    4
#define LQ    512
#define LKV   8192
#define QDIM  1024
#define KVDIM 512
#define QKCH  256
#define VCH   256
#define NH    8
#define DHD   32
#define EPS_LN 1e-5f

typedef __attribute__((ext_vector_type(8))) short bf16x8;
typedef __attribute__((ext_vector_type(4))) float f32x4;

__device__ __forceinline__ ushort f2bf(float x) {
    unsigned int u = __builtin_bit_cast(unsigned int, x);
    u += 0x7FFFu + ((u >> 16) & 1u);          // round-to-nearest-even
    return (ushort)(u >> 16);
}
__device__ __forceinline__ float bf2f(ushort b) {
    return __builtin_bit_cast(float, (unsigned int)b << 16);
}

// ---------------------------------------------------------------------------
// LayerNorm statistics: one block per row, writes mean and rstd only.
// ---------------------------------------------------------------------------
template<int K>
__global__ __launch_bounds__(256) void ln_stats_kernel(
    const float* __restrict__ x, float* __restrict__ mean, float* __restrict__ rstd)
{
    __shared__ float sm[4];
    constexpr int PT = K / 256;
    const size_t base = (size_t)blockIdx.x * K;
    float loc[PT];
    float s = 0.f;
#pragma unroll
    for (int i = 0; i < PT; ++i) {
        loc[i] = x[base + threadIdx.x + i * 256];
        s += loc[i];
    }
#pragma unroll
    for (int o = 32; o; o >>= 1) s += __shfl_down(s, o, 64);
    if ((threadIdx.x & 63) == 0) sm[threadIdx.x >> 6] = s;
    __syncthreads();
    const float mu = (sm[0] + sm[1] + sm[2] + sm[3]) * (1.0f / K);
    __syncthreads();
    float vs = 0.f;
#pragma unroll
    for (int i = 0; i < PT; ++i) { float d = loc[i] - mu; vs += d * d; }
#pragma unroll
    for (int o = 32; o; o >>= 1) vs += __shfl_down(vs, o, 64);
    if ((threadIdx.x & 63) == 0) sm[threadIdx.x >> 6] = vs;
    __syncthreads();
    if (threadIdx.x == 0) {
        mean[blockIdx.x] = mu;
        rstd[blockIdx.x] = rsqrtf((sm[0] + sm[1] + sm[2] + sm[3]) * (1.0f / K) + EPS_LN);
    }
}

// ---------------------------------------------------------------------------
// Y = LayerNorm(X[M,K]) @ W[K,N] + bias, written as bf16 in attention layouts.
// MODE 0: q[bh][tok][32]  (scaled by oscale)   LOGTOK=9
// MODE 1: k[bh][tok][32]                        LOGTOK=13
// MODE 2: vT[bh][32][tok] (transposed)          LOGTOK=13
// 64x64 tile, BK=16, 256 threads, 4x4 micro-tile per thread, fp32 compute.
// ---------------------------------------------------------------------------
template<int MODE, int LOGTOK>
__global__ __launch_bounds__(256) void gemm_ln_bias_bf16(
    const float* __restrict__ X,
    const float* __restrict__ mean, const float* __restrict__ rstd,
    const float* __restrict__ lng,  const float* __restrict__ lnb,
    const float* __restrict__ W,    const float* __restrict__ bias,
    ushort* __restrict__ Y, int M, int N, int K, float oscale)
{
    __shared__ float Xs[16][68];
    __shared__ float Ws[16][64];

    const int bm = blockIdx.x * 64;
    const int bn = blockIdx.y * 64;
    const int t  = threadIdx.x;
    const int tm = (t >> 4) << 2;
    const int tn = (t & 15) << 2;
    const int lr = t >> 2;
    const int lk = (t & 3) << 2;
    const int wk = t >> 4;
    const int wn = (t & 15) << 2;

    const int   xrow = bm + lr;
    const float mu   = mean[xrow];
    const float rs   = rstd[xrow];
    const float* xp  = X + (size_t)xrow * K;

    float acc[4][4] = {{0.f}};

    for (int k0 = 0; k0 < K; k0 += 16) {
        const float4 xv = *(const float4*)(xp + k0 + lk);
        const float4 gv = *(const float4*)(lng + k0 + lk);
        const float4 b2 = *(const float4*)(lnb + k0 + lk);
        Xs[lk + 0][lr] = (xv.x - mu) * rs * gv.x + b2.x;
        Xs[lk + 1][lr] = (xv.y - mu) * rs * gv.y + b2.y;
        Xs[lk + 2][lr] = (xv.z - mu) * rs * gv.z + b2.z;
        Xs[lk + 3][lr] = (xv.w - mu) * rs * gv.w + b2.w;
        *(float4*)&Ws[wk][wn] = *(const float4*)(W + (size_t)(k0 + wk) * N + bn + wn);
        __syncthreads();
#pragma unroll
        for (int kk = 0; kk < 16; ++kk) {
            const float4 a = *(const float4*)&Xs[kk][tm];
            const float4 b = *(const float4*)&Ws[kk][tn];
            acc[0][0] += a.x * b.x; acc[0][1] += a.x * b.y; acc[0][2] += a.x * b.z; acc[0][3] += a.x * b.w;
            acc[1][0] += a.y * b.x; acc[1][1] += a.y * b.y; acc[1][2] += a.y * b.z; acc[1][3] += a.y * b.w;
            acc[2][0] += a.z * b.x; acc[2][1] += a.z * b.y; acc[2][2] += a.z * b.z; acc[2][3] += a.z * b.w;
            acc[3][0] += a.w * b.x; acc[3][1] += a.w * b.y; acc[3][2] += a.w * b.z; acc[3][3] += a.w * b.w;
        }
        __syncthreads();
    }

    const float4 bb = *(const float4*)(bias + bn + tn);
    const int tokmask = (1 << LOGTOK) - 1;

    if (MODE < 2) {
        // rows -> (b, tok); cols tn..tn+3 all within head h, dims d..d+3
        const int c = bn + tn;
        const int h = c >> 5;
        const int d = c & 31;
#pragma unroll
        for (int i = 0; i < 4; ++i) {
            const int r   = bm + tm + i;
            const int bb_ = r >> LOGTOK;
            const int tok = r & tokmask;
            ushort4 o;
            o.x = f2bf((acc[i][0] + bb.x) * oscale);
            o.y = f2bf((acc[i][1] + bb.y) * oscale);
            o.z = f2bf((acc[i][2] + bb.z) * oscale);
            o.w = f2bf((acc[i][3] + bb.w) * oscale);
            *(ushort4*)(Y + (((size_t)(bb_ * NH + h) << LOGTOK) + tok) * 32 + d) = o;
        }
    } else {
        // transposed: vT[bh][d][tok]; rows i = consecutive tokens
        const int r0  = bm + tm;
        const int bb_ = r0 >> LOGTOK;
        const int tok = r0 & tokmask;
        const float bj[4] = {bb.x, bb.y, bb.z, bb.w};
#pragma unroll
        for (int j = 0; j < 4; ++j) {
            const int c = bn + tn + j;
            const int h = c >> 5;
            const int d = c & 31;
            ushort4 o;
            o.x = f2bf(acc[0][j] + bj[j]);
            o.y = f2bf(acc[1][j] + bj[j]);
            o.z = f2bf(acc[2][j] + bj[j]);
            o.w = f2bf(acc[3][j] + bj[j]);
            *(ushort4*)(Y + ((size_t)(bb_ * NH + h) * 32 + d) * LKV + tok) = o;
        }
    }
}

// ---------------------------------------------------------------------------
// MFMA flash attention. Grid: (LQ/32, B*H), 256 threads = 4 waves.
// Each wave owns an independent KV chunk of 2048 (online softmax per wave),
// no in-loop barriers. Per 32-KV tile:
//   S^T[kv][q] = K·Q^T  (A=K-frag, B=Q-frag; both direct global b128 loads)
//   softmax over kv = rows: per-lane partial (8 vals) + shfl_xor(16,32)
//   P -> bf16 -> LDS [q][kv] (4x ds_write_b64), read 2x b128 B-frags
//   O^T[d][q] += V^T·P^T  (A=V-frag from vT, contiguous)
// Final: cross-wave combine via LDS.
// Fragment layouts (m89/m120-verified): A/B: outer=lane&15, k=(lane>>4)*8+j;
// C/D: col=lane&15, row=(lane>>4)*4+reg.
// ---------------------------------------------------------------------------
__global__ __launch_bounds__(256) void attn_mfma_kernel(
    const ushort* __restrict__ Qb,  // [B*H][LQ][32] bf16, pre-scaled by 1/sqrt(32)
    const ushort* __restrict__ Kb,  // [B*H][LKV][32]
    const ushort* __restrict__ Vt,  // [B*H][32][LKV]
    float* __restrict__ Out)        // [B][LQ][256]
{
    const int bh = blockIdx.y;
    const int b  = bh >> 3;
    const int h  = bh & 7;
    const int qt = blockIdx.x;
    const int t  = threadIdx.x;
    const int w  = t >> 6;
    const int lane = t & 63;
    const int lq = lane & 15;     // fragment "outer"/col index
    const int lg = lane >> 4;     // group 0..3

    __shared__ ushort Pb[4][32][40];     // per-wave P bf16, [q][kv], stride 40 (80B, 16B-mult)
    __shared__ float  Obuf[4][32][36];   // per-wave scaled O, [q][d]
    __shared__ float  mbuf[4][32], lbuf[4][32], glbuf[32];

    // Q B-fragments for q-tiles 0,16: lane holds Q[q=nt+lq][d=lg*8+j]
    const size_t qbase = ((size_t)bh * LQ + qt * 32) * 32;
    bf16x8 qfrag[2];
    qfrag[0] = *(const bf16x8*)(Qb + qbase + (size_t)lq * 32 + lg * 8);
    qfrag[1] = *(const bf16x8*)(Qb + qbase + (size_t)(16 + lq) * 32 + lg * 8);

    // per-wave KV chunk base pointers (fragment-lane resolved)
    const ushort* KpA = Kb + ((size_t)bh * LKV + w * 2048 + lq) * 32 + lg * 8;
    const ushort* VpA = Vt + ((size_t)bh * 32 + lq) * LKV + w * 2048 + lg * 8;

    f32x4 oacc[2][2] = {};               // [m=d-tile][n=q-tile]
    float m_run[2] = {-1e30f, -1e30f};
    float l_run[2] = {0.f, 0.f};

    ushort* myP = &Pb[w][0][0];

    // prefetch tile 0
    bf16x8 kf0 = *(const bf16x8*)(KpA + 0 * 32);
    bf16x8 kf1 = *(const bf16x8*)(KpA + 16 * 32);
    bf16x8 vf0 = *(const bf16x8*)(VpA + (size_t)0 * LKV + 0);
    bf16x8 vf1 = *(const bf16x8*)(VpA + (size_t)16 * LKV + 0);

    for (int kt = 0; kt < 2048; kt += 32) {
        const bf16x8 kc0 = kf0, kc1 = kf1, vc0 = vf0, vc1 = vf1;
        const int nk = (kt + 32 < 2048) ? (kt + 32) : 0;   // clamp: harmless re-read
        kf0 = *(const bf16x8*)(KpA + (size_t)(nk + 0)  * 32);
        kf1 = *(const bf16x8*)(KpA + (size_t)(nk + 16) * 32);
        vf0 = *(const bf16x8*)(VpA + (size_t)0  * LKV + nk);
        vf1 = *(const bf16x8*)(VpA + (size_t)16 * LKV + nk);

        // S^T = K · Q^T : s[m=kv-tile][n=q-tile]
        f32x4 zero = {0.f, 0.f, 0.f, 0.f};
        f32x4 s[2][2];
        s[0][0] = __builtin_amdgcn_mfma_f32_16x16x32_bf16(kc0, qfrag[0], zero, 0, 0, 0);
        s[0][1] = __builtin_amdgcn_mfma_f32_16x16x32_bf16(kc0, qfrag[1], zero, 0, 0, 0);
        s[1][0] = __builtin_amdgcn_mfma_f32_16x16x32_bf16(kc1, qfrag[0], zero, 0, 0, 0);
        s[1][1] = __builtin_amdgcn_mfma_f32_16x16x32_bf16(kc1, qfrag[1], zero, 0, 0, 0);

        uint2 pw[2][2];
#pragma unroll
        for (int n = 0; n < 2; ++n) {
            // max over kv (rows): 8 per-lane values + cross-group reduce
            float pm = s[0][n][0];
            pm = fmaxf(pm, s[0][n][1]); pm = fmaxf(pm, s[0][n][2]); pm = fmaxf(pm, s[0][n][3]);
            pm = fmaxf(pm, s[1][n][0]); pm = fmaxf(pm, s[1][n][1]);
            pm = fmaxf(pm, s[1][n][2]); pm = fmaxf(pm, s[1][n][3]);
            pm = fmaxf(pm, __shfl_xor(pm, 16));
            pm = fmaxf(pm, __shfl_xor(pm, 32));
            const float mnew = fmaxf(m_run[n], pm);
            const float a = __expf(m_run[n] - mnew);
            m_run[n] = mnew;

            float ps = 0.f;
#pragma unroll
            for (int m = 0; m < 2; ++m) {
                ushort pb[4];
#pragma unroll
                for (int r = 0; r < 4; ++r) {
                    const float p = __expf(s[m][n][r] - mnew);
                    pb[r] = f2bf(p);
                    ps += bf2f(pb[r]);     // l from rounded P: consistent with PV
                }
                pw[m][n].x = (unsigned int)pb[0] | ((unsigned int)pb[1] << 16);
                pw[m][n].y = (unsigned int)pb[2] | ((unsigned int)pb[3] << 16);
            }
            ps += __shfl_xor(ps, 16);
            ps += __shfl_xor(ps, 32);
            l_run[n] = l_run[n] * a + ps;
            oacc[0][n] *= a;
            oacc[1][n] *= a;
        }

        // P -> LDS [q][kv] (regs are kv-consecutive -> b64)
#pragma unroll
        for (int n = 0; n < 2; ++n)
#pragma unroll
            for (int m = 0; m < 2; ++m)
                *(uint2*)(myP + (n * 16 + lq) * 40 + m * 16 + lg * 4) = pw[m][n];

        // B-fragments of P^T: lane reads P[q=nt+lq][kv=lg*8..+7]
        bf16x8 pf0 = *(const bf16x8*)(myP + (size_t)lq * 40 + lg * 8);
        bf16x8 pf1 = *(const bf16x8*)(myP + (size_t)(16 + lq) * 40 + lg * 8);

        // O^T += V^T · P^T
        oacc[0][0] = __builtin_amdgcn_mfma_f32_16x16x32_bf16(vc0, pf0, oacc[0][0], 0, 0, 0);
        oacc[0][1] = __builtin_amdgcn_mfma_f32_16x16x32_bf16(vc0, pf1, oacc[0][1], 0, 0, 0);
        oacc[1][0] = __builtin_amdgcn_mfma_f32_16x16x32_bf16(vc1, pf0, oacc[1][0], 0, 0, 0);
        oacc[1][1] = __builtin_amdgcn_mfma_f32_16x16x32_bf16(vc1, pf1, oacc[1][1], 0, 0, 0);
    }

    // ---- cross-wave combine ----
    if (lg == 0) {
        mbuf[w][lq]      = m_run[0];  mbuf[w][16 + lq] = m_run[1];
        lbuf[w][lq]      = l_run[0];  lbuf[w][16 + lq] = l_run[1];
    }
    __syncthreads();

#pragma unroll
    for (int n = 0; n < 2; ++n) {
        const int q = n * 16 + lq;
        const float m0 = mbuf[0][q], m1 = mbuf[1][q], m2 = mbuf[2][q], m3 = mbuf[3][q];
        const float gm = fmaxf(fmaxf(m0, m1), fmaxf(m2, m3));
        const float gl = lbuf[0][q] * __expf(m0 - gm) + lbuf[1][q] * __expf(m1 - gm)
                       + lbuf[2][q] * __expf(m2 - gm) + lbuf[3][q] * __expf(m3 - gm);
        const float f = __expf(m_run[n] - gm);
#pragma unroll
        for (int m = 0; m < 2; ++m) {
            f32x4 v = oacc[m][n];
            v *= f;
            *(f32x4*)&Obuf[w][q][m * 16 + lg * 4] = v;
        }
        if (w == 0 && lg == 0) glbuf[q] = gl;
    }
    __syncthreads();

    {
        const int q  = t >> 3;
        const int d0 = (t & 7) * 4;
        f32x4 sum = *(const f32x4*)&Obuf[0][q][d0];
        sum += *(const f32x4*)&Obuf[1][q][d0];
        sum += *(const f32x4*)&Obuf[2][q][d0];
        sum += *(const f32x4*)&Obuf[3][q][d0];
        const float inv = 1.0f / glbuf[q];
        sum *= inv;
        *(f32x4*)(Out + ((size_t)(b * LQ + qt * 32 + q)) * 256 + h * 32 + d0) = sum;
    }
}

// ---------------------------------------------------------------------------
extern "C" void kernel_launch(void* const* d_in, const int* in_sizes, int n_in,
                              void* d_out, int out_size, void* d_ws, size_t ws_size,
                              hipStream_t stream)
{
    const float* hidden = (const float*)d_in[0];
    const float* inputs = (const float*)d_in[1];
    const float* ln1g   = (const float*)d_in[2];
    const float* ln1b   = (const float*)d_in[3];
    const float* ln2g   = (const float*)d_in[4];
    const float* ln2b   = (const float*)d_in[5];
    const float* Wq     = (const float*)d_in[6];
    const float* bq     = (const float*)d_in[7];
    const float* Wk     = (const float*)d_in[8];
    const float* bk     = (const float*)d_in[9];
    const float* Wv     = (const float*)d_in[10];
    const float* bv     = (const float*)d_in[11];
    float* out = (float*)d_out;

    float* ws = (float*)d_ws;
    float* mean_h = ws;                      // 2048
    float* rstd_h = ws + 2048;               // 2048
    float* mean_i = ws + 4096;               // 32768
    float* rstd_i = ws + 36864;              // 32768
    ushort* qb = (ushort*)(ws + 69632);                  // 32*512*32   = 0.5M elems
    ushort* kb = qb + (size_t)NB * NH * LQ * 32;         // 32*8192*32  = 8M elems
    ushort* vt = kb + (size_t)NB * NH * LKV * 32;        // 8M elems

    ln_stats_kernel<QDIM><<<NB * LQ, 256, 0, stream>>>(hidden, mean_h, rstd_h);
    ln_stats_kernel<KVDIM><<<NB * LKV, 256, 0, stream>>>(inputs, mean_i, rstd_i);

    const float qscale = 0.17677669529663687f;   // 1/sqrt(32)

    dim3 gq(NB * LQ / 64, QKCH / 64);
    gemm_ln_bias_bf16<0, 9><<<gq, 256, 0, stream>>>(hidden, mean_h, rstd_h, ln1g, ln1b,
                                                    Wq, bq, qb, NB * LQ, QKCH, QDIM, qscale);
    dim3 gk(NB * LKV / 64, QKCH / 64);
    gemm_ln_bias_bf16<1, 13><<<gk, 256, 0, stream>>>(inputs, mean_i, rstd_i, ln2g, ln2b,
                                                     Wk, bk, kb, NB * LKV, QKCH, KVDIM, 1.0f);
    gemm_ln_bias_bf16<2, 13><<<gk, 256, 0, stream>>>(inputs, mean_i, rstd_i, ln2g, ln2b,
                                                     Wv, bv, vt, NB * LKV, VCH, KVDIM, 1.0f);

    dim3 ga(LQ / 32, NB * NH);
    attn_mfma_kernel<<<ga, 256, 0, stream>>>(qb, kb, vt, out);
}

// Round 3
// 246.654 us; speedup vs baseline: 5.5589x; 2.1942x over previous
//
#include <hip/hip_runtime.h>
#include <hip/hip_bf16.h>
#include <math.h>

// Problem constants
#define NB    4
#define LQ    512
#define LKV   8192
#define QDIM  1024
#define KVDIM 512
#define NH    8
#define EPS_LN 1e-5f

typedef __attribute__((ext_vector_type(8))) short bf16x8;
typedef __attribute__((ext_vector_type(4))) float f32x4;

static __device__ __forceinline__ ushort f2bf(float x) {
    unsigned int u = __builtin_bit_cast(unsigned int, x);
    u += 0x7FFFu + ((u >> 16) & 1u);          // round-to-nearest-even
    return (ushort)(u >> 16);
}
static __device__ __forceinline__ float bf2f(ushort b) {
    return __builtin_bit_cast(float, (unsigned int)b << 16);
}
// async global->LDS, 16B per lane; LDS dest = wave base + lane*16
static __device__ __forceinline__ void gld_lds16(const ushort* g, ushort* l) {
    __builtin_amdgcn_global_load_lds(
        (const __attribute__((address_space(1))) unsigned int*)g,
        (__attribute__((address_space(3))) unsigned int*)l, 16, 0, 0);
}

// ---------------------------------------------------------------------------
// Fused LN normalize -> bf16.  One wave per row; block = 4 rows.
// y[row][k] = (x-mu)*rstd*g + b, rounded to bf16.
// ---------------------------------------------------------------------------
template<int K>
__global__ __launch_bounds__(256) void ln_norm_kernel(
    const float* __restrict__ x, const float* __restrict__ g,
    const float* __restrict__ bta, ushort* __restrict__ y)
{
    const int lane = threadIdx.x & 63;
    const int row  = blockIdx.x * 4 + (threadIdx.x >> 6);
    const float* xp = x + (size_t)row * K;
    constexpr int NV = K / 256;               // float4 per lane
    float4 v[NV];
    float s = 0.f;
#pragma unroll
    for (int i = 0; i < NV; ++i) {
        v[i] = *(const float4*)(xp + lane * 4 + i * 256);
        s += v[i].x + v[i].y + v[i].z + v[i].w;
    }
#pragma unroll
    for (int o = 1; o < 64; o <<= 1) s += __shfl_xor(s, o, 64);
    const float mu = s * (1.0f / K);
    float vs = 0.f;
#pragma unroll
    for (int i = 0; i < NV; ++i) {
        float dx = v[i].x - mu, dy = v[i].y - mu, dz = v[i].z - mu, dw = v[i].w - mu;
        vs += dx * dx + dy * dy + dz * dz + dw * dw;
    }
#pragma unroll
    for (int o = 1; o < 64; o <<= 1) vs += __shfl_xor(vs, o, 64);
    const float rs = rsqrtf(vs * (1.0f / K) + EPS_LN);
#pragma unroll
    for (int i = 0; i < NV; ++i) {
        const float4 gv = *(const float4*)(g   + lane * 4 + i * 256);
        const float4 bv = *(const float4*)(bta + lane * 4 + i * 256);
        ushort4 o;
        o.x = f2bf((v[i].x - mu) * rs * gv.x + bv.x);
        o.y = f2bf((v[i].y - mu) * rs * gv.y + bv.y);
        o.z = f2bf((v[i].z - mu) * rs * gv.z + bv.z);
        o.w = f2bf((v[i].w - mu) * rs * gv.w + bv.w);
        *(ushort4*)(y + (size_t)row * K + lane * 4 + i * 256) = o;
    }
}

// ---------------------------------------------------------------------------
// Weight transpose+convert: WtKV[n][k] (n<256: Wk col n; else Wv col n-256),
// WtQ[n][k] = Wq[k][n].  Grid 768: blocks 0..511 -> KV, 512..767 -> Q.
// ---------------------------------------------------------------------------
__global__ __launch_bounds__(256) void wt_convert_kernel(
    const float* __restrict__ Wq, const float* __restrict__ Wk,
    const float* __restrict__ Wv, ushort* __restrict__ WtQ,
    ushort* __restrict__ WtKV)
{
    const int n = blockIdx.x;
    const int t = threadIdx.x;
    if (n < 512) {
        const float* src; int col;
        if (n < 256) { src = Wk; col = n; } else { src = Wv; col = n - 256; }
#pragma unroll
        for (int i = 0; i < 2; ++i) {
            const int k = t + i * 256;
            WtKV[(size_t)n * 512 + k] = f2bf(src[(size_t)k * 256 + col]);
        }
    } else {
        const int nq = n - 512;
#pragma unroll
        for (int i = 0; i < 4; ++i) {
            const int k = t + i * 256;
            WtQ[(size_t)nq * 1024 + k] = f2bf(Wq[(size_t)k * 256 + nq]);
        }
    }
}

// ---------------------------------------------------------------------------
// bf16 MFMA GEMM (m97 structure): C[m][n] = A[m][:] . Wt[n][:], fp32 acc.
// 128x128 tile, BK=32, 256 thr = 4 waves in 2x2, each wave 4x4 16x16 tiles.
// Staging via global_load_lds width=16.  Epilogue writes attention layouts:
//   n < 256: K/Q style  out0[((b*NH+h)<<LOGTOK | tok)*32 + d], *oscale, +b0[n]
//   n >=256: V^T style  out1[((b*NH+h)*32 + d)*LKV + tok], +b1[n-256]
// ---------------------------------------------------------------------------
template<int TK, int LOGTOK>
__global__ __launch_bounds__(256) void mfma_gemm_kernel(
    const ushort* __restrict__ A, const ushort* __restrict__ Wt,
    const float* __restrict__ b0, const float* __restrict__ b1,
    ushort* __restrict__ out0, ushort* __restrict__ out1, float oscale)
{
    __shared__ __align__(16) ushort As[128 * 32];
    __shared__ __align__(16) ushort Bs[128 * 32];

    const int t    = threadIdx.x;
    const int lane = t & 63;
    const int w    = t >> 6;
    const int lq   = lane & 15;
    const int lg   = lane >> 4;
    const int wm   = w >> 1;
    const int wn   = w & 1;
    const int bm   = blockIdx.x * 128;
    const int bn   = blockIdx.y * 128;

    const ushort* gA = A  + (size_t)(bm + (t >> 2)) * TK + (t & 3) * 8;
    const ushort* gB = Wt + (size_t)(bn + (t >> 2)) * TK + (t & 3) * 8;
    ushort* lA = As + t * 8;
    ushort* lB = Bs + t * 8;

    f32x4 acc[4][4] = {};

    for (int k0 = 0; k0 < TK; k0 += 32) {
        gld_lds16(gA + k0,                      lA);
        gld_lds16(gA + (size_t)64 * TK + k0,    lA + 2048);
        gld_lds16(gB + k0,                      lB);
        gld_lds16(gB + (size_t)64 * TK + k0,    lB + 2048);
        __syncthreads();

        bf16x8 af[4], bf[4];
#pragma unroll
        for (int mt = 0; mt < 4; ++mt)
            af[mt] = *(const bf16x8*)(As + (wm * 64 + mt * 16 + lq) * 32 + lg * 8);
#pragma unroll
        for (int nt = 0; nt < 4; ++nt)
            bf[nt] = *(const bf16x8*)(Bs + (wn * 64 + nt * 16 + lq) * 32 + lg * 8);
#pragma unroll
        for (int mt = 0; mt < 4; ++mt)
#pragma unroll
            for (int nt = 0; nt < 4; ++nt)
                acc[mt][nt] = __builtin_amdgcn_mfma_f32_16x16x32_bf16(af[mt], bf[nt], acc[mt][nt], 0, 0, 0);
        __syncthreads();
    }

    constexpr int tokmask = (1 << LOGTOK) - 1;
#pragma unroll
    for (int nt = 0; nt < 4; ++nt) {
        const int n = bn + wn * 64 + nt * 16 + lq;
        if (n < 256) {
            const int h = n >> 5, d = n & 31;
            const float bias = b0[n];
#pragma unroll
            for (int mt = 0; mt < 4; ++mt) {
                const int m0   = bm + wm * 64 + mt * 16 + lg * 4;
                const int bidx = m0 >> LOGTOK;
                const int tok  = m0 & tokmask;
                const size_t base = (((size_t)(bidx * NH + h) << LOGTOK) + tok) * 32 + d;
#pragma unroll
                for (int r = 0; r < 4; ++r)
                    out0[base + (size_t)r * 32] = f2bf((acc[mt][nt][r] + bias) * oscale);
            }
        } else {
            const int nv = n - 256;
            const int h = nv >> 5, d = nv & 31;
            const float bias = b1[nv];
#pragma unroll
            for (int mt = 0; mt < 4; ++mt) {
                const int m0   = bm + wm * 64 + mt * 16 + lg * 4;
                const int bidx = m0 >> LOGTOK;
                const int tok  = m0 & tokmask;
                ushort4 o;
                o.x = f2bf(acc[mt][nt][0] + bias);
                o.y = f2bf(acc[mt][nt][1] + bias);
                o.z = f2bf(acc[mt][nt][2] + bias);
                o.w = f2bf(acc[mt][nt][3] + bias);
                *(ushort4*)(out1 + ((size_t)(bidx * NH + h) * 32 + d) * LKV + tok) = o;
            }
        }
    }
}

// ---------------------------------------------------------------------------
// MFMA flash attention, q-tile 64. Grid (LQ/64, B*H), 512 thr = 8 waves.
// Wave w owns KV chunk [w*1024, w*1024+1024), 32 iterations of 32 KV.
// Per iter: S^T = K.Q^T (8 MFMA), online softmax (reg + shfl), P->LDS->
// B-frag, O^T += V^T.P^T (8 MFMA). No in-loop barriers. 8-wave combine.
// ---------------------------------------------------------------------------
__global__ __launch_bounds__(512, 1) void attn_mfma_kernel(
    const ushort* __restrict__ Qb,  // [B*H][LQ][32] bf16, pre-scaled
    const ushort* __restrict__ Kb,  // [B*H][LKV][32]
    const ushort* __restrict__ Vt,  // [B*H][32][LKV]
    float* __restrict__ Out)        // [B][LQ][256]
{
    const int bh = blockIdx.y, b = bh >> 3, h = bh & 7;
    const int qt = blockIdx.x;
    const int t  = threadIdx.x, w = t >> 6, lane = t & 63;
    const int lq = lane & 15, lg = lane >> 4;

    __shared__ __align__(16) ushort Pb[8][64][40];   // per-wave P; aliased as Ob (f32) post-loop
    __shared__ float mbuf[8][64], lbuf[8][64], glbuf[64];

    bf16x8 qfrag[4];
    const size_t qbase = ((size_t)bh * LQ + qt * 64) * 32;
#pragma unroll
    for (int n = 0; n < 4; ++n)
        qfrag[n] = *(const bf16x8*)(Qb + qbase + (size_t)(n * 16 + lq) * 32 + lg * 8);

    const ushort* KpA = Kb + ((size_t)bh * LKV + w * 1024 + lq) * 32 + lg * 8;
    const ushort* VpA = Vt + ((size_t)bh * 32 + lq) * LKV + w * 1024 + lg * 8;

    f32x4 oacc[2][4] = {};
    float m_run[4] = {-1e30f, -1e30f, -1e30f, -1e30f};
    float l_run[4] = {0.f, 0.f, 0.f, 0.f};
    ushort* myP = &Pb[w][0][0];

    bf16x8 kf0 = *(const bf16x8*)(KpA);
    bf16x8 kf1 = *(const bf16x8*)(KpA + 16 * 32);
    bf16x8 vf0 = *(const bf16x8*)(VpA);
    bf16x8 vf1 = *(const bf16x8*)(VpA + (size_t)16 * LKV);

    for (int kt = 0; kt < 1024; kt += 32) {
        const bf16x8 kc0 = kf0, kc1 = kf1, vc0 = vf0, vc1 = vf1;
        const int nk = (kt + 32 < 1024) ? kt + 32 : 0;   // clamp: harmless re-read
        kf0 = *(const bf16x8*)(KpA + (size_t)nk * 32);
        kf1 = *(const bf16x8*)(KpA + (size_t)(nk + 16) * 32);
        vf0 = *(const bf16x8*)(VpA + nk);
        vf1 = *(const bf16x8*)(VpA + (size_t)16 * LKV + nk);

        const f32x4 zero = {0.f, 0.f, 0.f, 0.f};
        f32x4 s[2][4];
#pragma unroll
        for (int n = 0; n < 4; ++n) {
            s[0][n] = __builtin_amdgcn_mfma_f32_16x16x32_bf16(kc0, qfrag[n], zero, 0, 0, 0);
            s[1][n] = __builtin_amdgcn_mfma_f32_16x16x32_bf16(kc1, qfrag[n], zero, 0, 0, 0);
        }

        uint2 pw[2][4];
#pragma unroll
        for (int n = 0; n < 4; ++n) {
            float pm = s[0][n][0];
            pm = fmaxf(pm, s[0][n][1]); pm = fmaxf(pm, s[0][n][2]); pm = fmaxf(pm, s[0][n][3]);
            pm = fmaxf(pm, s[1][n][0]); pm = fmaxf(pm, s[1][n][1]);
            pm = fmaxf(pm, s[1][n][2]); pm = fmaxf(pm, s[1][n][3]);
            pm = fmaxf(pm, __shfl_xor(pm, 16));
            pm = fmaxf(pm, __shfl_xor(pm, 32));
            const float mnew = fmaxf(m_run[n], pm);
            const float a = __expf(m_run[n] - mnew);
            m_run[n] = mnew;

            float ps = 0.f;
#pragma unroll
            for (int m = 0; m < 2; ++m) {
                ushort pb[4];
#pragma unroll
                for (int r = 0; r < 4; ++r) {
                    const float p = __expf(s[m][n][r] - mnew);
                    pb[r] = f2bf(p);
                    ps += bf2f(pb[r]);            // l from rounded P, consistent with PV
                }
                pw[m][n].x = (unsigned int)pb[0] | ((unsigned int)pb[1] << 16);
                pw[m][n].y = (unsigned int)pb[2] | ((unsigned int)pb[3] << 16);
            }
            ps += __shfl_xor(ps, 16);
            ps += __shfl_xor(ps, 32);
            l_run[n] = l_run[n] * a + ps;
            oacc[0][n] *= a;
            oacc[1][n] *= a;
        }

#pragma unroll
        for (int n = 0; n < 4; ++n)
#pragma unroll
            for (int m = 0; m < 2; ++m)
                *(uint2*)(myP + (n * 16 + lq) * 40 + m * 16 + lg * 4) = pw[m][n];

        bf16x8 pf[4];
#pragma unroll
        for (int n = 0; n < 4; ++n)
            pf[n] = *(const bf16x8*)(myP + (size_t)(n * 16 + lq) * 40 + lg * 8);

#pragma unroll
        for (int n = 0; n < 4; ++n) {
            oacc[0][n] = __builtin_amdgcn_mfma_f32_16x16x32_bf16(vc0, pf[n], oacc[0][n], 0, 0, 0);
            oacc[1][n] = __builtin_amdgcn_mfma_f32_16x16x32_bf16(vc1, pf[n], oacc[1][n], 0, 0, 0);
        }
    }

    // ---- 8-wave combine ----
    if (lg == 0) {
#pragma unroll
        for (int n = 0; n < 4; ++n) {
            mbuf[w][n * 16 + lq] = m_run[n];
            lbuf[w][n * 16 + lq] = l_run[n];
        }
    }
    __syncthreads();   // all waves done with loop; mbuf/lbuf visible

    float* Ob = (float*)&Pb[0][0][0];   // [4][64][40] f32 scratch (aliases Pb)
#pragma unroll
    for (int n = 0; n < 4; ++n) {
        const int q = n * 16 + lq;
        float gm = mbuf[0][q];
#pragma unroll
        for (int j = 1; j < 8; ++j) gm = fmaxf(gm, mbuf[j][q]);
        float gl = 0.f;
#pragma unroll
        for (int j = 0; j < 8; ++j) gl += lbuf[j][q] * __expf(mbuf[j][q] - gm);
        const float f = __expf(m_run[n] - gm);
        oacc[0][n] *= f;
        oacc[1][n] *= f;
        if (w == 0 && lg == 0) glbuf[q] = gl;
    }

    if (w >= 4) {
        const int wj = w - 4;
#pragma unroll
        for (int n = 0; n < 4; ++n)
#pragma unroll
            for (int m = 0; m < 2; ++m)
                *(f32x4*)&Ob[((size_t)wj * 64 + n * 16 + lq) * 40 + m * 16 + lg * 4] = oacc[m][n];
    }
    __syncthreads();
    if (w < 4) {
#pragma unroll
        for (int n = 0; n < 4; ++n)
#pragma unroll
            for (int m = 0; m < 2; ++m) {
                float* p = &Ob[((size_t)w * 64 + n * 16 + lq) * 40 + m * 16 + lg * 4];
                f32x4 v = *(f32x4*)p;
                v += oacc[m][n];
                *(f32x4*)p = v;
            }
    }
    __syncthreads();
    {
        const int q = t >> 3, d0 = (t & 7) * 4;
        f32x4 sum = *(const f32x4*)&Ob[((size_t)0 * 64 + q) * 40 + d0];
        sum += *(const f32x4*)&Ob[((size_t)1 * 64 + q) * 40 + d0];
        sum += *(const f32x4*)&Ob[((size_t)2 * 64 + q) * 40 + d0];
        sum += *(const f32x4*)&Ob[((size_t)3 * 64 + q) * 40 + d0];
        sum *= (1.0f / glbuf[q]);
        *(f32x4*)(Out + ((size_t)b * LQ + qt * 64 + q) * 256 + h * 32 + d0) = sum;
    }
}

// ---------------------------------------------------------------------------
extern "C" void kernel_launch(void* const* d_in, const int* in_sizes, int n_in,
                              void* d_out, int out_size, void* d_ws, size_t ws_size,
                              hipStream_t stream)
{
    const float* hidden = (const float*)d_in[0];
    const float* inputs = (const float*)d_in[1];
    const float* ln1g   = (const float*)d_in[2];
    const float* ln1b   = (const float*)d_in[3];
    const float* ln2g   = (const float*)d_in[4];
    const float* ln2b   = (const float*)d_in[5];
    const float* Wq     = (const float*)d_in[6];
    const float* bq     = (const float*)d_in[7];
    const float* Wk     = (const float*)d_in[8];
    const float* bk     = (const float*)d_in[9];
    const float* Wv     = (const float*)d_in[10];
    const float* bv     = (const float*)d_in[11];
    float* out = (float*)d_out;

    // workspace layout (bytes), peak 66 MB:
    char* wsb = (char*)d_ws;
    ushort* qb   = (ushort*)(wsb);                        //  1 MB  [32][512][32]
    ushort* WtKV = (ushort*)(wsb + (1u << 20));           //  0.5MB [512][512]
    ushort* WtQ  = (ushort*)(wsb + (1u << 20) + (512u << 10)); // 0.5MB [256][1024]
    ushort* kb   = (ushort*)(wsb + (2u << 20));           // 16 MB  [32][8192][32]
    ushort* vt   = (ushort*)(wsb + (18u << 20));          // 16 MB  [32][32][8192]
    ushort* Abf  = (ushort*)(wsb + (34u << 20));          // 32 MB  [32768][512] (KV)
    ushort* AbfQ = Abf;                                   //  4 MB  [2048][1024] (aliased; Q chain runs first)

    const float qscale = 0.17677669529663687f;   // 1/sqrt(32)

    // Q chain (uses Abf region first, then it is overwritten by KV norm)
    ln_norm_kernel<QDIM><<<NB * LQ / 4, 256, 0, stream>>>(hidden, ln1g, ln1b, AbfQ);
    wt_convert_kernel<<<768, 256, 0, stream>>>(Wq, Wk, Wv, WtQ, WtKV);
    {
        dim3 g(NB * LQ / 128, 256 / 128);
        mfma_gemm_kernel<QDIM, 9><<<g, 256, 0, stream>>>(AbfQ, WtQ, bq, nullptr,
                                                         qb, nullptr, qscale);
    }
    // KV chain
    ln_norm_kernel<KVDIM><<<NB * LKV / 4, 256, 0, stream>>>(inputs, ln2g, ln2b, Abf);
    {
        dim3 g(NB * LKV / 128, 512 / 128);
        mfma_gemm_kernel<KVDIM, 13><<<g, 256, 0, stream>>>(Abf, WtKV, bk, bv,
                                                           kb, vt, 1.0f);
    }
    // attention
    {
        dim3 g(LQ / 64, NB * NH);
        attn_mfma_kernel<<<g, 512, 0, stream>>>(qb, kb, vt, out);
    }
}

// Round 4
// 223.595 us; speedup vs baseline: 6.1322x; 1.1031x over previous
//
#include <hip/hip_runtime.h>
#include <hip/hip_bf16.h>
#include <math.h>

// Problem constants
#define NB    4
#define LQ    512
#define LKV   8192
#define QDIM  1024
#define KVDIM 512
#define NH    8
#define EPS_LN 1e-5f

typedef __attribute__((ext_vector_type(8))) short bf16x8;
typedef __attribute__((ext_vector_type(4))) float f32x4;

static __device__ __forceinline__ ushort f2bf(float x) {
    unsigned int u = __builtin_bit_cast(unsigned int, x);
    u += 0x7FFFu + ((u >> 16) & 1u);          // round-to-nearest-even
    return (ushort)(u >> 16);
}

#if __has_builtin(__builtin_amdgcn_cvt_pk_bf16_f32)
static __device__ __forceinline__ unsigned int pk_bf16(float a, float b) {
    auto r = __builtin_amdgcn_cvt_pk_bf16_f32(a, b);   // low = a, high = b
    return __builtin_bit_cast(unsigned int, r);
}
#else
static __device__ __forceinline__ unsigned int pk_bf16(float a, float b) {
    return (unsigned int)f2bf(a) | ((unsigned int)f2bf(b) << 16);
}
#endif

#if __has_builtin(__builtin_amdgcn_exp2f)
#define EXP2F(x) __builtin_amdgcn_exp2f(x)
#else
#define EXP2F(x) exp2f(x)
#endif

// async global->LDS, 16B per lane; LDS dest = wave base + lane*16
static __device__ __forceinline__ void gld_lds16(const ushort* g, ushort* l) {
    __builtin_amdgcn_global_load_lds(
        (const __attribute__((address_space(1))) unsigned int*)g,
        (__attribute__((address_space(3))) unsigned int*)l, 16, 0, 0);
}

// ---------------------------------------------------------------------------
// Fused LN normalize -> bf16.  One wave per row; block = 4 rows.
// ---------------------------------------------------------------------------
template<int K>
__global__ __launch_bounds__(256) void ln_norm_kernel(
    const float* __restrict__ x, const float* __restrict__ g,
    const float* __restrict__ bta, ushort* __restrict__ y)
{
    const int lane = threadIdx.x & 63;
    const int row  = blockIdx.x * 4 + (threadIdx.x >> 6);
    const float* xp = x + (size_t)row * K;
    constexpr int NV = K / 256;               // float4 per lane
    float4 v[NV];
    float s = 0.f;
#pragma unroll
    for (int i = 0; i < NV; ++i) {
        v[i] = *(const float4*)(xp + lane * 4 + i * 256);
        s += v[i].x + v[i].y + v[i].z + v[i].w;
    }
#pragma unroll
    for (int o = 1; o < 64; o <<= 1) s += __shfl_xor(s, o, 64);
    const float mu = s * (1.0f / K);
    float vs = 0.f;
#pragma unroll
    for (int i = 0; i < NV; ++i) {
        float dx = v[i].x - mu, dy = v[i].y - mu, dz = v[i].z - mu, dw = v[i].w - mu;
        vs += dx * dx + dy * dy + dz * dz + dw * dw;
    }
#pragma unroll
    for (int o = 1; o < 64; o <<= 1) vs += __shfl_xor(vs, o, 64);
    const float rs = rsqrtf(vs * (1.0f / K) + EPS_LN);
#pragma unroll
    for (int i = 0; i < NV; ++i) {
        const float4 gv = *(const float4*)(g   + lane * 4 + i * 256);
        const float4 bv = *(const float4*)(bta + lane * 4 + i * 256);
        ushort2 o0, o1;
        unsigned int u0 = pk_bf16((v[i].x - mu) * rs * gv.x + bv.x,
                                  (v[i].y - mu) * rs * gv.y + bv.y);
        unsigned int u1 = pk_bf16((v[i].z - mu) * rs * gv.z + bv.z,
                                  (v[i].w - mu) * rs * gv.w + bv.w);
        uint2 o; o.x = u0; o.y = u1;
        *(uint2*)(y + (size_t)row * K + lane * 4 + i * 256) = o;
    }
}

// ---------------------------------------------------------------------------
// Tiled weight transpose+convert: dst[n][k] = bf16(src[k][n]).  64x64 tiles.
// Coalesced global reads (lanes along n), coalesced 16B writes (along k).
// ---------------------------------------------------------------------------
__global__ __launch_bounds__(256) void wt_transpose_kernel(
    const float* __restrict__ src, ushort* __restrict__ dst, int K, int N)
{
    __shared__ ushort Ts[64][72];   // row stride 144B (16B mult for b128 reads)
    const int t  = threadIdx.x;
    const int k0 = blockIdx.x * 64;
    const int n0 = blockIdx.y * 64;
    const int nl = t & 63;
#pragma unroll
    for (int p = 0; p < 16; ++p) {
        const int kl = p * 4 + (t >> 6);
        Ts[nl][kl] = f2bf(src[(size_t)(k0 + kl) * N + n0 + nl]);
    }
    __syncthreads();
    const int ck = (t & 7) * 8;
#pragma unroll
    for (int p = 0; p < 2; ++p) {
        const int rn = p * 32 + (t >> 3);
        *(bf16x8*)(dst + (size_t)(n0 + rn) * K + k0 + ck) = *(const bf16x8*)&Ts[rn][ck];
    }
}

// ---------------------------------------------------------------------------
// KV projection GEMM: C[m][n] = A[m][:] . Wt[n][:], bf16 MFMA, fp32 acc.
// 128x128 tile, BK=32, 256 thr = 4 waves (2x2), each wave 4x4 16-tiles.
// XOR-swizzled LDS (kills 8-way ds_read_b128 conflicts on 64B rows).
// Epilogue: bn<256 -> K layout direct; bn>=256 -> V^T via LDS transpose.
// ---------------------------------------------------------------------------
__global__ __launch_bounds__(256) void gemm_kv_kernel(
    const ushort* __restrict__ A, const ushort* __restrict__ Wt,
    const float* __restrict__ b0, const float* __restrict__ b1,
    ushort* __restrict__ out0, ushort* __restrict__ out1)
{
    __shared__ __align__(16) ushort SM[4][64][72];    // 36864B; staging aliases front 16KB
    ushort* As = &SM[0][0][0];
    ushort* Bs = As + 4096;

    const int t    = threadIdx.x;
    const int lane = t & 63;
    const int w    = t >> 6;
    const int lq   = lane & 15;
    const int lg   = lane >> 4;
    const int wm   = w >> 1;
    const int wn   = w & 1;
    const int bm   = blockIdx.x * 128;
    const int bn   = blockIdx.y * 128;

    const int srow = t >> 2;                              // 0..63
    const int scol = ((t & 3) ^ ((t >> 3) & 3)) * 8;      // xor-swizzled source col
    const ushort* gA = A  + (size_t)(bm + srow) * KVDIM + scol;
    const ushort* gB = Wt + (size_t)(bn + srow) * KVDIM + scol;
    ushort* lA = As + t * 8;
    ushort* lB = Bs + t * 8;

    f32x4 acc[4][4] = {};

    for (int k0 = 0; k0 < KVDIM; k0 += 32) {
        gld_lds16(gA + k0,                       lA);
        gld_lds16(gA + (size_t)64 * KVDIM + k0,  lA + 2048);
        gld_lds16(gB + k0,                       lB);
        gld_lds16(gB + (size_t)64 * KVDIM + k0,  lB + 2048);
        __syncthreads();

        bf16x8 af[4], bf[4];
#pragma unroll
        for (int mt = 0; mt < 4; ++mt) {
            const int m = wm * 64 + mt * 16 + lq;
            af[mt] = *(const bf16x8*)(As + m * 32 + ((lg ^ ((m >> 1) & 3)) << 3));
        }
#pragma unroll
        for (int nt = 0; nt < 4; ++nt) {
            const int n = wn * 64 + nt * 16 + lq;
            bf[nt] = *(const bf16x8*)(Bs + n * 32 + ((lg ^ ((n >> 1) & 3)) << 3));
        }
#pragma unroll
        for (int mt = 0; mt < 4; ++mt)
#pragma unroll
            for (int nt = 0; nt < 4; ++nt)
                acc[mt][nt] = __builtin_amdgcn_mfma_f32_16x16x32_bf16(af[mt], bf[nt], acc[mt][nt], 0, 0, 0);
        __syncthreads();
    }

    if (bn < 256) {
        // ---- K path: [bh][tok][32] direct ----
#pragma unroll
        for (int nt = 0; nt < 4; ++nt) {
            const int n = bn + wn * 64 + nt * 16 + lq;
            const int h = n >> 5, d = n & 31;
            const float bias = b0[n];
#pragma unroll
            for (int mt = 0; mt < 4; ++mt) {
                const int m0   = bm + wm * 64 + mt * 16 + lg * 4;
                const int bidx = m0 >> 13;
                const int tok  = m0 & 8191;
                const size_t base = (((size_t)(bidx * NH + h) << 13) + tok) * 32 + d;
#pragma unroll
                for (int r = 0; r < 4; ++r)
                    out0[base + (size_t)r * 32] = f2bf(acc[mt][nt][r] + bias);
            }
        }
    } else {
        // ---- V path: vT[bh][d][tok] via per-wave LDS transpose ----
        ushort (*Cs)[72] = (ushort(*)[72])&SM[w][0][0];
#pragma unroll
        for (int nt = 0; nt < 4; ++nt) {
            const int n_l = nt * 16 + lq;
            const float bias = b1[(bn - 256) + wn * 64 + n_l];
#pragma unroll
            for (int mt = 0; mt < 4; ++mt) {
                uint2 o;
                o.x = pk_bf16(acc[mt][nt][0] + bias, acc[mt][nt][1] + bias);
                o.y = pk_bf16(acc[mt][nt][2] + bias, acc[mt][nt][3] + bias);
                *(uint2*)&Cs[n_l][mt * 16 + lg * 4] = o;
            }
        }
        const int r0 = lane >> 3;
        const int cm = (lane & 7) * 8;
        const int m0base = bm + wm * 64;
        const int bidx   = m0base >> 13;
        const int tokb   = (m0base & 8191) + cm;
#pragma unroll
        for (int p = 0; p < 8; ++p) {
            const int row = p * 8 + r0;
            const int nv  = (bn - 256) + wn * 64 + row;
            const int h = nv >> 5, d = nv & 31;
            *(bf16x8*)(out1 + ((size_t)(bidx * NH + h) * 32 + d) * LKV + tokb) =
                *(const bf16x8*)&Cs[row][cm];
        }
    }
}

// ---------------------------------------------------------------------------
// Q projection GEMM: 64x64 tile, BK=64, grid (32,4)=128 blocks.
// Output scaled by oscale (log2e/sqrt(32)) in Q layout [bh][tok][32].
// ---------------------------------------------------------------------------
__global__ __launch_bounds__(256) void gemm_q_kernel(
    const ushort* __restrict__ A, const ushort* __restrict__ Wt,
    const float* __restrict__ b0, ushort* __restrict__ out0, float oscale)
{
    __shared__ __align__(16) ushort As[64 * 64];
    __shared__ __align__(16) ushort Bs[64 * 64];

    const int t    = threadIdx.x;
    const int lane = t & 63;
    const int w    = t >> 6;
    const int lq   = lane & 15;
    const int lg   = lane >> 4;
    const int wm   = w >> 1;
    const int wn   = w & 1;
    const int bm   = blockIdx.x * 64;
    const int bn   = blockIdx.y * 64;

    const int srow = t >> 3;                              // 0..31
    const int scol = ((t & 7) ^ ((t >> 3) & 7)) * 8;      // xor-swizzled source col
    const ushort* gA = A  + (size_t)(bm + srow) * QDIM + scol;
    const ushort* gB = Wt + (size_t)(bn + srow) * QDIM + scol;
    ushort* lA = As + t * 8;
    ushort* lB = Bs + t * 8;

    f32x4 acc[2][2] = {};

    for (int k0 = 0; k0 < QDIM; k0 += 64) {
        gld_lds16(gA + k0,                      lA);
        gld_lds16(gA + (size_t)32 * QDIM + k0,  lA + 2048);
        gld_lds16(gB + k0,                      lB);
        gld_lds16(gB + (size_t)32 * QDIM + k0,  lB + 2048);
        __syncthreads();
#pragma unroll
        for (int kh = 0; kh < 2; ++kh) {
            bf16x8 af[2], bf[2];
#pragma unroll
            for (int mt = 0; mt < 2; ++mt) {
                const int m = wm * 32 + mt * 16 + lq;
                af[mt] = *(const bf16x8*)(As + m * 64 + (((lg + 4 * kh) ^ (m & 7)) << 3));
            }
#pragma unroll
            for (int nt = 0; nt < 2; ++nt) {
                const int n = wn * 32 + nt * 16 + lq;
                bf[nt] = *(const bf16x8*)(Bs + n * 64 + (((lg + 4 * kh) ^ (n & 7)) << 3));
            }
#pragma unroll
            for (int mt = 0; mt < 2; ++mt)
#pragma unroll
                for (int nt = 0; nt < 2; ++nt)
                    acc[mt][nt] = __builtin_amdgcn_mfma_f32_16x16x32_bf16(af[mt], bf[nt], acc[mt][nt], 0, 0, 0);
        }
        __syncthreads();
    }

#pragma unroll
    for (int nt = 0; nt < 2; ++nt) {
        const int n = bn + wn * 32 + nt * 16 + lq;
        const int h = n >> 5, d = n & 31;
        const float bias = b0[n];
#pragma unroll
        for (int mt = 0; mt < 2; ++mt) {
            const int m0   = bm + wm * 32 + mt * 16 + lg * 4;
            const int bidx = m0 >> 9;
            const int tok  = m0 & 511;
            const size_t base = (((size_t)(bidx * NH + h) << 9) + tok) * 32 + d;
#pragma unroll
            for (int r = 0; r < 4; ++r)
                out0[base + (size_t)r * 32] = f2bf((acc[mt][nt][r] + bias) * oscale);
        }
    }
}

// ---------------------------------------------------------------------------
// MFMA flash attention, log2-domain softmax. Grid 512 (1D, XCD-swizzled),
// 512 thr = 8 waves. q-tile 32; wave w owns KV chunk [w*1024, +1024).
// Per 32-KV iter: S^T = K.Q^T (4 MFMA), softmax (exp2, packed cvt),
// P->LDS->B-frag, O^T += V^T.P^T (4 MFMA). No in-loop barriers.
// ---------------------------------------------------------------------------
__global__ __launch_bounds__(512, 4) void attn_mfma_kernel(
    const ushort* __restrict__ Qb,  // [B*H][LQ][32] bf16, pre-scaled by log2e/sqrt(32)
    const ushort* __restrict__ Kb,  // [B*H][LKV][32]
    const ushort* __restrict__ Vt,  // [B*H][32][LKV]
    float* __restrict__ Out)        // [B][LQ][256]
{
    // XCD-aware decode: all 16 q-tiles of a bh stay on one XCD (L2 reuse).
    const int bid = blockIdx.x;
    const int xcd = bid & 7;
    const int rr  = bid >> 3;
    const int bh  = ((rr & 3) << 3) | xcd;
    const int qt  = rr >> 2;                 // 0..15
    const int b = bh >> 3, h = bh & 7;
    const int t = threadIdx.x, w = t >> 6, lane = t & 63;
    const int lq = lane & 15, lg = lane >> 4;

    __shared__ __align__(16) ushort Pb[8][32][40];   // per-wave P; aliased as Ob f32 post-loop
    __shared__ float mbuf[8][32], lbuf[8][32], glbuf[32];

    bf16x8 qfrag[2];
    const size_t qbase = ((size_t)bh * LQ + qt * 32) * 32;
#pragma unroll
    for (int n = 0; n < 2; ++n)
        qfrag[n] = *(const bf16x8*)(Qb + qbase + (size_t)(n * 16 + lq) * 32 + lg * 8);

    const ushort* KpA = Kb + ((size_t)bh * LKV + w * 1024 + lq) * 32 + lg * 8;
    const ushort* VpA = Vt + ((size_t)bh * 32 + lq) * LKV + w * 1024 + lg * 8;

    f32x4 oacc[2][2] = {};
    float m_run[2] = {-1e30f, -1e30f};
    float l_run[2] = {0.f, 0.f};
    ushort* myP = &Pb[w][0][0];

    bf16x8 kf0 = *(const bf16x8*)(KpA);
    bf16x8 kf1 = *(const bf16x8*)(KpA + 16 * 32);
    bf16x8 vf0 = *(const bf16x8*)(VpA);
    bf16x8 vf1 = *(const bf16x8*)(VpA + (size_t)16 * LKV);

    for (int kt = 0; kt < 1024; kt += 32) {
        const bf16x8 kc0 = kf0, kc1 = kf1, vc0 = vf0, vc1 = vf1;
        const int nk = (kt + 32 < 1024) ? kt + 32 : 0;   // clamp: harmless re-read
        kf0 = *(const bf16x8*)(KpA + (size_t)nk * 32);
        kf1 = *(const bf16x8*)(KpA + (size_t)(nk + 16) * 32);
        vf0 = *(const bf16x8*)(VpA + nk);
        vf1 = *(const bf16x8*)(VpA + (size_t)16 * LKV + nk);

        const f32x4 zero = {0.f, 0.f, 0.f, 0.f};
        f32x4 s[2][2];
#pragma unroll
        for (int n = 0; n < 2; ++n) {
            s[0][n] = __builtin_amdgcn_mfma_f32_16x16x32_bf16(kc0, qfrag[n], zero, 0, 0, 0);
            s[1][n] = __builtin_amdgcn_mfma_f32_16x16x32_bf16(kc1, qfrag[n], zero, 0, 0, 0);
        }

        uint2 pw[2][2];
#pragma unroll
        for (int n = 0; n < 2; ++n) {
            float pm = fmaxf(fmaxf(fmaxf(s[0][n][0], s[0][n][1]), fmaxf(s[0][n][2], s[0][n][3])),
                             fmaxf(fmaxf(s[1][n][0], s[1][n][1]), fmaxf(s[1][n][2], s[1][n][3])));
            pm = fmaxf(pm, __shfl_xor(pm, 16));
            pm = fmaxf(pm, __shfl_xor(pm, 32));
            const float mnew = fmaxf(m_run[n], pm);
            const float a = EXP2F(m_run[n] - mnew);   // log2 domain
            m_run[n] = mnew;

            float ps = 0.f;
#pragma unroll
            for (int m = 0; m < 2; ++m) {
                float p0 = EXP2F(s[m][n][0] - mnew);
                float p1 = EXP2F(s[m][n][1] - mnew);
                float p2 = EXP2F(s[m][n][2] - mnew);
                float p3 = EXP2F(s[m][n][3] - mnew);
                ps += (p0 + p1) + (p2 + p3);
                pw[m][n].x = pk_bf16(p0, p1);
                pw[m][n].y = pk_bf16(p2, p3);
            }
            ps += __shfl_xor(ps, 16);
            ps += __shfl_xor(ps, 32);
            l_run[n] = l_run[n] * a + ps;
            oacc[0][n] *= a;
            oacc[1][n] *= a;
        }

#pragma unroll
        for (int n = 0; n < 2; ++n)
#pragma unroll
            for (int m = 0; m < 2; ++m)
                *(uint2*)(myP + (n * 16 + lq) * 40 + m * 16 + lg * 4) = pw[m][n];

        bf16x8 pf[2];
#pragma unroll
        for (int n = 0; n < 2; ++n)
            pf[n] = *(const bf16x8*)(myP + (size_t)(n * 16 + lq) * 40 + lg * 8);

#pragma unroll
        for (int n = 0; n < 2; ++n) {
            oacc[0][n] = __builtin_amdgcn_mfma_f32_16x16x32_bf16(vc0, pf[n], oacc[0][n], 0, 0, 0);
            oacc[1][n] = __builtin_amdgcn_mfma_f32_16x16x32_bf16(vc1, pf[n], oacc[1][n], 0, 0, 0);
        }
    }

    // ---- 8-wave combine ----
    if (lg == 0) {
#pragma unroll
        for (int n = 0; n < 2; ++n) {
            mbuf[w][n * 16 + lq] = m_run[n];
            lbuf[w][n * 16 + lq] = l_run[n];
        }
    }
    __syncthreads();

    float* Ob = (float*)&Pb[0][0][0];   // [4][32][40] f32 scratch (aliases all of Pb)
#pragma unroll
    for (int n = 0; n < 2; ++n) {
        const int q = n * 16 + lq;
        float gm = mbuf[0][q];
#pragma unroll
        for (int j = 1; j < 8; ++j) gm = fmaxf(gm, mbuf[j][q]);
        float gl = 0.f;
#pragma unroll
        for (int j = 0; j < 8; ++j) gl += lbuf[j][q] * EXP2F(mbuf[j][q] - gm);
        const float f = EXP2F(m_run[n] - gm);
        oacc[0][n] *= f;
        oacc[1][n] *= f;
        if (w == 0 && lg == 0) glbuf[q] = gl;
    }

    if (w >= 4) {
        const int wj = w - 4;
#pragma unroll
        for (int n = 0; n < 2; ++n)
#pragma unroll
            for (int m = 0; m < 2; ++m)
                *(f32x4*)&Ob[((size_t)wj * 32 + n * 16 + lq) * 40 + m * 16 + lg * 4] = oacc[m][n];
    }
    __syncthreads();
    if (w < 4) {
#pragma unroll
        for (int n = 0; n < 2; ++n)
#pragma unroll
            for (int m = 0; m < 2; ++m) {
                float* p = &Ob[((size_t)w * 32 + n * 16 + lq) * 40 + m * 16 + lg * 4];
                f32x4 v = *(f32x4*)p;
                v += oacc[m][n];
                *(f32x4*)p = v;
            }
    }
    __syncthreads();
    {
        const int q = t >> 4, d0 = (t & 15) * 2;
        float s0 = 0.f, s1 = 0.f;
#pragma unroll
        for (int j = 0; j < 4; ++j) {
            s0 += Ob[((size_t)j * 32 + q) * 40 + d0];
            s1 += Ob[((size_t)j * 32 + q) * 40 + d0 + 1];
        }
        const float inv = 1.0f / glbuf[q];
        float2 o; o.x = s0 * inv; o.y = s1 * inv;
        *(float2*)(Out + ((size_t)b * LQ + qt * 32 + q) * 256 + h * 32 + d0) = o;
    }
}

// ---------------------------------------------------------------------------
extern "C" void kernel_launch(void* const* d_in, const int* in_sizes, int n_in,
                              void* d_out, int out_size, void* d_ws, size_t ws_size,
                              hipStream_t stream)
{
    const float* hidden = (const float*)d_in[0];
    const float* inputs = (const float*)d_in[1];
    const float* ln1g   = (const float*)d_in[2];
    const float* ln1b   = (const float*)d_in[3];
    const float* ln2g   = (const float*)d_in[4];
    const float* ln2b   = (const float*)d_in[5];
    const float* Wq     = (const float*)d_in[6];
    const float* bq     = (const float*)d_in[7];
    const float* Wk     = (const float*)d_in[8];
    const float* bk     = (const float*)d_in[9];
    const float* Wv     = (const float*)d_in[10];
    const float* bv     = (const float*)d_in[11];
    float* out = (float*)d_out;

    // workspace layout (bytes), peak 66 MB:
    char* wsb = (char*)d_ws;
    ushort* qb   = (ushort*)(wsb);                               //  1 MB  [32][512][32]
    ushort* WtKV = (ushort*)(wsb + (1u << 20));                  //  0.5MB [512][512]
    ushort* WtQ  = (ushort*)(wsb + (1u << 20) + (512u << 10));   //  0.5MB [256][1024]
    ushort* kb   = (ushort*)(wsb + (2u << 20));                  // 16 MB  [32][8192][32]
    ushort* vt   = (ushort*)(wsb + (18u << 20));                 // 16 MB  [32][32][8192]
    ushort* Abf  = (ushort*)(wsb + (34u << 20));                 // 32 MB  [32768][512] (KV)
    ushort* AbfQ = Abf;                                          //  4 MB  [2048][1024] (aliased; Q chain first)

    const float oscale = 0.2550540226496112f;   // log2(e)/sqrt(32): log2-domain softmax

    // Q chain
    ln_norm_kernel<QDIM><<<NB * LQ / 4, 256, 0, stream>>>(hidden, ln1g, ln1b, AbfQ);
    wt_transpose_kernel<<<dim3(QDIM / 64, 256 / 64), 256, 0, stream>>>(Wq, WtQ, QDIM, 256);
    {
        dim3 g(NB * LQ / 64, 256 / 64);
        gemm_q_kernel<<<g, 256, 0, stream>>>(AbfQ, WtQ, bq, qb, oscale);
    }
    // KV chain
    wt_transpose_kernel<<<dim3(KVDIM / 64, 256 / 64), 256, 0, stream>>>(Wk, WtKV, KVDIM, 256);
    wt_transpose_kernel<<<dim3(KVDIM / 64, 256 / 64), 256, 0, stream>>>(Wv, WtKV + (size_t)256 * KVDIM, KVDIM, 256);
    ln_norm_kernel<KVDIM><<<NB * LKV / 4, 256, 0, stream>>>(inputs, ln2g, ln2b, Abf);
    {
        dim3 g(NB * LKV / 128, 512 / 128);
        gemm_kv_kernel<<<g, 256, 0, stream>>>(Abf, WtKV, bk, bv, kb, vt);
    }
    // attention
    attn_mfma_kernel<<<512, 512, 0, stream>>>(qb, kb, vt, out);
}